// Round 7
// baseline (755.620 us; speedup 1.0000x reference)
//
#include <hip/hip_runtime.h>

// VQ-VAE VectorQuantizer: x[32768,256] fp32, emb[256,1024] fp32.
// Round 7: rescue chain gets explicit register-array load batching (the r6
// version compiled to 32 VGPRs -> zero memory-level parallelism -> 420us of
// pure latency). Chunked 16-d prefetch: 16 global loads + 4 ds_read_b128 in
// flight per chunk. Chain order and all rounding bit-identical to r4/r6.

#define D 256
#define K 1024
#define N_PTS 32768

typedef __attribute__((ext_vector_type(8))) short short8v;   // 8 bf16 (4 VGPR)
typedef __attribute__((ext_vector_type(4))) float f32x4;     // MFMA acc
typedef __attribute__((ext_vector_type(4))) unsigned short us4v;

__device__ __forceinline__ unsigned short bf16rne(float f) {
    unsigned u = __float_as_uint(f);                 // finite data, no NaN
    return (unsigned short)((u + 0x7FFFu + ((u >> 16) & 1u)) >> 16);
}

// ws layout (bytes):
//   0        float  enorm[1024]        4 KB   (numpy-sequential fp32 ||e||^2)
//   8192     double lossacc            8 B
//   16384    float  Anorm[32768]       128 KB (numpy pairwise ||x||^2)
//   147456   float  Sabs[32768]        128 KB (sum|x| for margin bound)
//   409600   ushort ehT[1024][256]     512 KB (bf16, code-major)
//   933888   float  embT[1024][256]    1 MB   (f32, code-major, merge gather)
//   1982464  float  gmin16[32768][64]  8 MB
// xh bf16 [32768][256] (16 MB) lives in d_out scratch.

// ---- consolidated prep: blocks 0-255 prepx, 256-259 enorm, 260-323 prepe ----
__global__ __launch_bounds__(256) void vq_prep(const float* __restrict__ x,
                                               const float* __restrict__ emb,
                                               float* __restrict__ Anorm,
                                               float* __restrict__ Sabs,
                                               unsigned short* __restrict__ xh,
                                               float* __restrict__ enorm,
                                               float* __restrict__ embT,
                                               unsigned short* __restrict__ ehT) {
    __shared__ float tile[64][68];
    const int b = blockIdx.x;
    const int tid = threadIdx.x;

    if (b < 256) {
        // ---- prepx: Anorm (numpy pairwise), Sabs, xh bf16 ----
        const int gt = b * 256 + tid;
        const int n  = gt >> 1;
        const int h  = gt & 1;
        const float4* __restrict__ xr =
            reinterpret_cast<const float4*>(x + (size_t)n * D) + h * 32;
        unsigned short* __restrict__ xo = xh + (size_t)n * D + h * 128;

        float r[8], sab;
        float4 u = xr[0], v = xr[1];
        {
            short8v p;
            p[0]=(short)bf16rne(u.x); p[1]=(short)bf16rne(u.y);
            p[2]=(short)bf16rne(u.z); p[3]=(short)bf16rne(u.w);
            p[4]=(short)bf16rne(v.x); p[5]=(short)bf16rne(v.y);
            p[6]=(short)bf16rne(v.z); p[7]=(short)bf16rne(v.w);
            *reinterpret_cast<short8v*>(xo) = p;
        }
        r[0]=__fmul_rn(u.x,u.x); r[1]=__fmul_rn(u.y,u.y);
        r[2]=__fmul_rn(u.z,u.z); r[3]=__fmul_rn(u.w,u.w);
        r[4]=__fmul_rn(v.x,v.x); r[5]=__fmul_rn(v.y,v.y);
        r[6]=__fmul_rn(v.z,v.z); r[7]=__fmul_rn(v.w,v.w);
        sab = fabsf(u.x)+fabsf(u.y)+fabsf(u.z)+fabsf(u.w)
            + fabsf(v.x)+fabsf(v.y)+fabsf(v.z)+fabsf(v.w);
        #pragma unroll
        for (int i = 1; i < 16; ++i) {
            u = xr[2*i]; v = xr[2*i+1];
            short8v p;
            p[0]=(short)bf16rne(u.x); p[1]=(short)bf16rne(u.y);
            p[2]=(short)bf16rne(u.z); p[3]=(short)bf16rne(u.w);
            p[4]=(short)bf16rne(v.x); p[5]=(short)bf16rne(v.y);
            p[6]=(short)bf16rne(v.z); p[7]=(short)bf16rne(v.w);
            *reinterpret_cast<short8v*>(xo + i * 8) = p;
            r[0]=__fadd_rn(r[0],__fmul_rn(u.x,u.x));
            r[1]=__fadd_rn(r[1],__fmul_rn(u.y,u.y));
            r[2]=__fadd_rn(r[2],__fmul_rn(u.z,u.z));
            r[3]=__fadd_rn(r[3],__fmul_rn(u.w,u.w));
            r[4]=__fadd_rn(r[4],__fmul_rn(v.x,v.x));
            r[5]=__fadd_rn(r[5],__fmul_rn(v.y,v.y));
            r[6]=__fadd_rn(r[6],__fmul_rn(v.z,v.z));
            r[7]=__fadd_rn(r[7],__fmul_rn(v.w,v.w));
            sab += fabsf(u.x)+fabsf(u.y)+fabsf(u.z)+fabsf(u.w)
                 + fabsf(v.x)+fabsf(v.y)+fabsf(v.z)+fabsf(v.w);
        }
        float ah = __fadd_rn(__fadd_rn(__fadd_rn(r[0],r[1]),__fadd_rn(r[2],r[3])),
                             __fadd_rn(__fadd_rn(r[4],r[5]),__fadd_rn(r[6],r[7])));
        float oh = __shfl_xor(ah, 1);
        float os = __shfl_xor(sab, 1);
        if (h == 0) {
            Anorm[n] = __fadd_rn(ah, oh);   // fl(half0 + half1), numpy order
            Sabs[n]  = sab + os;
        }
    } else if (b < 260) {
        // ---- enorm: numpy axis-0 sequential fp32 sum of squares ----
        // explicit e[]/en[] register batches for MLP (coalesced 256B/wave-instr)
        int k = (b - 256) * 256 + tid;
        float c = 0.0f;
        float e[16], en[16];
        #pragma unroll
        for (int i = 0; i < 16; ++i) e[i] = emb[i * K + k];
        #pragma unroll
        for (int ch = 0; ch < 16; ++ch) {
            if (ch < 15) {
                #pragma unroll
                for (int i = 0; i < 16; ++i) en[i] = emb[((ch + 1) * 16 + i) * K + k];
            }
            #pragma unroll
            for (int i = 0; i < 16; ++i)
                c = __fadd_rn(c, __fmul_rn(e[i], e[i]));   // sequential d order
            #pragma unroll
            for (int i = 0; i < 16; ++i) e[i] = en[i];
        }
        enorm[k] = c;
    } else {
        // ---- prepe: embT f32 + ehT bf16 (code-major transposes) ----
        const int bb = b - 260;
        const int bk = bb >> 2, bd = bb & 3;
        const int k0 = bk * 64, d0 = bd * 64;
        #pragma unroll
        for (int s = 0; s < 4; ++s) {
            int li = s * 256 + tid;
            int dd = li >> 4, kq = li & 15;
            float4 v = *reinterpret_cast<const float4*>(
                &emb[(size_t)(d0 + dd) * K + k0 + kq * 4]);
            tile[dd][kq*4+0]=v.x; tile[dd][kq*4+1]=v.y;
            tile[dd][kq*4+2]=v.z; tile[dd][kq*4+3]=v.w;
        }
        __syncthreads();
        #pragma unroll
        for (int s = 0; s < 4; ++s) {
            int li = s * 256 + tid;
            int kk = li >> 4, dq = li & 15;
            float4 v;
            v.x = tile[dq*4+0][kk]; v.y = tile[dq*4+1][kk];
            v.z = tile[dq*4+2][kk]; v.w = tile[dq*4+3][kk];
            *reinterpret_cast<float4*>(&embT[(size_t)(k0+kk)*D + d0 + dq*4]) = v;
            us4v hq;
            hq[0]=bf16rne(v.x); hq[1]=bf16rne(v.y);
            hq[2]=bf16rne(v.z); hq[3]=bf16rne(v.w);
            *reinterpret_cast<us4v*>(&ehT[(size_t)(k0+kk)*D + d0 + dq*4]) = hq;
        }
    }
}

// ---- bf16 MFMA screen: 128x128 tile, 4 waves (2x2), 16x16x32 MFMA ----
#define LDSTR 40   // ushorts per LDS row (80B): 16B-aligned, 2-way banks (free)

__global__ __launch_bounds__(256) void vq_screen(const unsigned short* __restrict__ xh,
                                                 const unsigned short* __restrict__ ehT,
                                                 const float* __restrict__ Anorm,
                                                 const float* __restrict__ enorm,
                                                 float* __restrict__ gmin16) {
    __shared__ unsigned short a_lds[128 * LDSTR];
    __shared__ unsigned short b_lds[128 * LDSTR];
    const int tid = threadIdx.x;
    const int l = tid & 63, wid = tid >> 6;
    const int wr = wid >> 1, wc = wid & 1;        // wave tile 64x64
    const int rt = blockIdx.x >> 3, cc = blockIdx.x & 7;
    const int n0 = rt * 128, c0 = cc * 128;
    const int g = l >> 4, cl = l & 15;

    f32x4 acc[4][4];
    #pragma unroll
    for (int mf = 0; mf < 4; ++mf)
        #pragma unroll
        for (int nf = 0; nf < 4; ++nf)
            acc[mf][nf] = (f32x4){0.f, 0.f, 0.f, 0.f};

    const int srow = tid >> 1, sq = (tid & 1) * 2;   // staging: 2x16B per thread
    for (int s = 0; s < 8; ++s) {                    // K = 8 steps of 32
        __syncthreads();
        {
            const short8v* ga = reinterpret_cast<const short8v*>(
                xh + (size_t)(n0 + srow) * D + s * 32 + sq * 8);
            short8v a0 = ga[0], a1 = ga[1];
            *reinterpret_cast<short8v*>(&a_lds[srow * LDSTR + sq * 8])     = a0;
            *reinterpret_cast<short8v*>(&a_lds[srow * LDSTR + sq * 8 + 8]) = a1;
            const short8v* gb = reinterpret_cast<const short8v*>(
                ehT + (size_t)(c0 + srow) * D + s * 32 + sq * 8);
            short8v b0 = gb[0], b1 = gb[1];
            *reinterpret_cast<short8v*>(&b_lds[srow * LDSTR + sq * 8])     = b0;
            *reinterpret_cast<short8v*>(&b_lds[srow * LDSTR + sq * 8 + 8]) = b1;
        }
        __syncthreads();
        short8v af[4], bf[4];
        #pragma unroll
        for (int mf = 0; mf < 4; ++mf)
            af[mf] = *reinterpret_cast<const short8v*>(
                &a_lds[(wr * 64 + mf * 16 + cl) * LDSTR + g * 8]);
        #pragma unroll
        for (int nf = 0; nf < 4; ++nf)
            bf[nf] = *reinterpret_cast<const short8v*>(
                &b_lds[(wc * 64 + nf * 16 + cl) * LDSTR + g * 8]);
        #pragma unroll
        for (int mf = 0; mf < 4; ++mf)
            #pragma unroll
            for (int nf = 0; nf < 4; ++nf)
                acc[mf][nf] = __builtin_amdgcn_mfma_f32_16x16x32_bf16(
                    af[mf], bf[nf], acc[mf][nf], 0, 0, 0);
    }

    // epilogue: screen dist + per-row 16-code group mins
    #pragma unroll
    for (int mf = 0; mf < 4; ++mf) {
        #pragma unroll
        for (int nf = 0; nf < 4; ++nf) {
            f32x4 a = acc[mf][nf];
            const int cg = c0 + wc * 64 + nf * 16 + cl;
            const float C = enorm[cg];
            #pragma unroll
            for (int r = 0; r < 4; ++r) {
                const int ng = n0 + wr * 64 + mf * 16 + g * 4 + r;
                float dist = Anorm[ng] - 2.0f * a[r] + C;
                #pragma unroll
                for (int m = 1; m <= 8; m <<= 1)
                    dist = fminf(dist, __shfl_xor(dist, m));
                if (cl == 0)
                    gmin16[(size_t)ng * 64 + cc * 8 + wc * 4 + nf] = dist;
            }
        }
    }
}

// ---- fused exact rescue + gather/out/loss: one wave per row ----
__global__ __launch_bounds__(256, 4) void vq_rescue_merge(
        const float* __restrict__ x,
        const float* __restrict__ emb,
        const float* __restrict__ embT,
        const float* __restrict__ Anorm,
        const float* __restrict__ Sabs,
        const float* __restrict__ enorm,
        const float* __restrict__ gmin16,
        float* __restrict__ out,
        double* __restrict__ lossacc) {
    __shared__ float xs[4][256];   // one x row per wave, broadcast-read
    const int tid = threadIdx.x, l = tid & 63, w = tid >> 6;
    const int row = blockIdx.x * 4 + w;

    const float4 xv4 = reinterpret_cast<const float4*>(x + (size_t)row * D)[l];
    *reinterpret_cast<float4*>(&xs[w][l * 4]) = xv4;

    float gv = gmin16[(size_t)row * 64 + l];
    float gm = gv;
    #pragma unroll
    for (int m = 1; m < 64; m <<= 1) gm = fminf(gm, __shfl_xor(gm, m));
    // margin identical to the r4 PASSING run (sound: 2*per-code bf16 bound)
    const float margin = fmaf(Sabs[row] * 0.05f, 0.017f, 0.002f);
    unsigned long long mask = __ballot(gv <= gm + margin);

    __syncthreads();   // xs visible

    const float A = Anorm[row];
    const int p   = l >> 4;    // up to 4 groups per pass, one per lane-group
    const int sub = l & 15;
    float bestd = 1e30f; int besti = 0x7fffffff;
    const float4* __restrict__ xs4 = reinterpret_cast<const float4*>(xs[w]);

    while (mask) {
        unsigned long long m = mask;          // p-th set bit (mask wave-uniform)
        if (p > 0) m &= m - 1;
        if (p > 1 && m) m &= m - 1;
        if (p > 2 && m) m &= m - 1;
        const int gp = m ? __builtin_ctzll(m) : __builtin_ctzll(mask); // idle->dup g0
        #pragma unroll
        for (int i = 0; i < 4; ++i) mask &= mask - 1;   // strip <=4 bits (0-safe)

        const int k = gp * 16 + sub;
        const float* __restrict__ ek = emb + k;
        // EXACT reference chain (sequential-d fp32 fmaf), restructured for MLP:
        // explicit e[]/en[] register arrays hold 16 loads in flight per chunk,
        // x via ds_read_b128. Chain ORDER over d is unchanged -> bit-identical.
        float c = 0.f;
        float e[16], en[16];
        #pragma unroll
        for (int i = 0; i < 16; ++i) e[i] = ek[(size_t)i * K];
        #pragma unroll
        for (int ch = 0; ch < 16; ++ch) {
            if (ch < 15) {
                #pragma unroll
                for (int i = 0; i < 16; ++i)
                    en[i] = ek[(size_t)((ch + 1) * 16 + i) * K];
            }
            float4 x0 = xs4[ch * 4 + 0];
            float4 x1 = xs4[ch * 4 + 1];
            float4 x2 = xs4[ch * 4 + 2];
            float4 x3 = xs4[ch * 4 + 3];
            c = fmaf(x0.x, e[0],  c); c = fmaf(x0.y, e[1],  c);
            c = fmaf(x0.z, e[2],  c); c = fmaf(x0.w, e[3],  c);
            c = fmaf(x1.x, e[4],  c); c = fmaf(x1.y, e[5],  c);
            c = fmaf(x1.z, e[6],  c); c = fmaf(x1.w, e[7],  c);
            c = fmaf(x2.x, e[8],  c); c = fmaf(x2.y, e[9],  c);
            c = fmaf(x2.z, e[10], c); c = fmaf(x2.w, e[11], c);
            c = fmaf(x3.x, e[12], c); c = fmaf(x3.y, e[13], c);
            c = fmaf(x3.z, e[14], c); c = fmaf(x3.w, e[15], c);
            #pragma unroll
            for (int i = 0; i < 16; ++i) e[i] = en[i];    // reg rename, no cost
        }
        float dist = __fadd_rn(__fsub_rn(A, 2.0f * c), enorm[k]); // fl(fl(A-2B)+C)
        if (dist < bestd || (dist == bestd && k < besti)) { bestd = dist; besti = k; }
    }
    #pragma unroll
    for (int m = 1; m < 64; m <<= 1) {        // lexicographic (dist, idx) min
        float od = __shfl_xor(bestd, m);
        int   oi = __shfl_xor(besti, m);
        if (od < bestd || (od == bestd && oi < besti)) { bestd = od; besti = oi; }
    }
    besti = __shfl(besti, 0);

    // fused merge: gather winning code (code-major, coalesced), write, loss
    const float4 q = reinterpret_cast<const float4*>(embT + (size_t)besti * D)[l];
    reinterpret_cast<float4*>(out + (size_t)row * D)[l] = q;  // exact pass-through
    double lsum = 0.0, dxx;
    dxx = (double)q.x - (double)xv4.x; lsum = fma(dxx, dxx, lsum);
    dxx = (double)q.y - (double)xv4.y; lsum = fma(dxx, dxx, lsum);
    dxx = (double)q.z - (double)xv4.z; lsum = fma(dxx, dxx, lsum);
    dxx = (double)q.w - (double)xv4.w; lsum = fma(dxx, dxx, lsum);
    for (int off = 32; off > 0; off >>= 1) lsum += __shfl_down(lsum, off);
    if (l == 0) atomicAdd(lossacc, lsum);
}

__global__ void vq_loss(const double* __restrict__ lossacc, float* __restrict__ out_loss) {
    if (threadIdx.x == 0 && blockIdx.x == 0) {
        out_loss[0] = (float)(1.25 * (lossacc[0] / (double)((size_t)N_PTS * D)));
    }
}

extern "C" void kernel_launch(void* const* d_in, const int* in_sizes, int n_in,
                              void* d_out, int out_size, void* d_ws, size_t ws_size,
                              hipStream_t stream) {
    const float* x   = (const float*)d_in[0];
    const float* emb = (const float*)d_in[1];
    float* out = (float*)d_out;
    char* ws = (char*)d_ws;

    float*  enorm   = (float*)(ws);
    double* lossacc = (double*)(ws + 8192);
    float*  Anorm   = (float*)(ws + 16384);
    float*  Sabs    = (float*)(ws + 147456);
    unsigned short* ehT = (unsigned short*)(ws + 409600);
    float*  embT    = (float*)(ws + 933888);
    float*  gmin16  = (float*)(ws + 1982464);           // 8 MB, ends ~10.4 MB
    unsigned short* xh = (unsigned short*)out;          // d_out scratch

    hipMemsetAsync(lossacc, 0, sizeof(double), stream);
    vq_prep<<<256 + 4 + 64, 256, 0, stream>>>(x, emb, Anorm, Sabs, xh,
                                              enorm, embT, ehT);
    vq_screen<<<(N_PTS / 128) * (K / 128), 256, 0, stream>>>(xh, ehT, Anorm, enorm, gmin16);
    vq_rescue_merge<<<N_PTS / 4, 256, 0, stream>>>(x, emb, embT, Anorm, Sabs,
                                                   enorm, gmin16, out, lossacc);
    vq_loss<<<1, 64, 0, stream>>>(lossacc, out + (size_t)N_PTS * D);
}

// Round 8
// 601.574 us; speedup vs baseline: 1.2561x; 1.2561x over previous
//
#include <hip/hip_runtime.h>

// VQ-VAE VectorQuantizer: x[32768,256] fp32, emb[256,1024] fp32.
// Round 8: r7's e[16]/en[16] register ARRAYS were demoted to scratch
// (FETCH+WRITE ~2.6GB of spill traffic, 54% HBM on spills). Rewritten with
// NAMED SCALARS in a 2-bank ping-pong prefetch (16 loads in flight, zero
// copies). Chain order over d unchanged -> dist values bit-identical to the
// r4/r6 passing runs. Screen/prepx untouched.

#define D 256
#define K 1024
#define N_PTS 32768

typedef __attribute__((ext_vector_type(8))) short short8v;   // 8 bf16 (4 VGPR)
typedef __attribute__((ext_vector_type(4))) float f32x4;     // MFMA acc
typedef __attribute__((ext_vector_type(4))) unsigned short us4v;

__device__ __forceinline__ unsigned short bf16rne(float f) {
    unsigned u = __float_as_uint(f);                 // finite data, no NaN
    return (unsigned short)((u + 0x7FFFu + ((u >> 16) & 1u)) >> 16);
}

// ---- named-scalar load/compute macros (no arrays -> guaranteed VGPRs) ----
#define EDECL(p) float p##0, p##1, p##2, p##3, p##4, p##5, p##6, p##7;
#define LD8(p, base) \
    p##0 = ek[(size_t)((base)+0)*K]; p##1 = ek[(size_t)((base)+1)*K]; \
    p##2 = ek[(size_t)((base)+2)*K]; p##3 = ek[(size_t)((base)+3)*K]; \
    p##4 = ek[(size_t)((base)+4)*K]; p##5 = ek[(size_t)((base)+5)*K]; \
    p##6 = ek[(size_t)((base)+6)*K]; p##7 = ek[(size_t)((base)+7)*K];
#define FMA8(p, base) { \
    float4 xa_ = xs4[(base)>>2], xb_ = xs4[((base)>>2)+1]; \
    c = fmaf(xa_.x, p##0, c); c = fmaf(xa_.y, p##1, c); \
    c = fmaf(xa_.z, p##2, c); c = fmaf(xa_.w, p##3, c); \
    c = fmaf(xb_.x, p##4, c); c = fmaf(xb_.y, p##5, c); \
    c = fmaf(xb_.z, p##6, c); c = fmaf(xb_.w, p##7, c); }
#define SQ8(p) { \
    c = __fadd_rn(c, __fmul_rn(p##0, p##0)); c = __fadd_rn(c, __fmul_rn(p##1, p##1)); \
    c = __fadd_rn(c, __fmul_rn(p##2, p##2)); c = __fadd_rn(c, __fmul_rn(p##3, p##3)); \
    c = __fadd_rn(c, __fmul_rn(p##4, p##4)); c = __fadd_rn(c, __fmul_rn(p##5, p##5)); \
    c = __fadd_rn(c, __fmul_rn(p##6, p##6)); c = __fadd_rn(c, __fmul_rn(p##7, p##7)); }
// compute chunk b1 (bank a) + prefetch b1+16; compute b1+8 (bank b) + prefetch b1+24
#define STEP2(b1)  FMA8(ea, b1) LD8(ea, (b1)+16) FMA8(eb, (b1)+8) LD8(eb, (b1)+24)
#define STEP2E(b1) SQ8(ea) LD8(ea, (b1)+16) SQ8(eb) LD8(eb, (b1)+24)

// ws layout (bytes):
//   0        float  enorm[1024]        4 KB   (numpy-sequential fp32 ||e||^2)
//   8192     double lossacc            8 B
//   16384    float  Anorm[32768]       128 KB (numpy pairwise ||x||^2)
//   147456   float  Sabs[32768]        128 KB (sum|x| for margin bound)
//   409600   ushort ehT[1024][256]     512 KB (bf16, code-major)
//   933888   float  embT[1024][256]    1 MB   (f32, code-major, merge gather)
//   1982464  float  gmin16[32768][64]  8 MB
// xh bf16 [32768][256] (16 MB) lives in d_out scratch.

// ---- consolidated prep: blocks 0-255 prepx, 256-259 enorm, 260-323 prepe ----
__global__ __launch_bounds__(256) void vq_prep(const float* __restrict__ x,
                                               const float* __restrict__ emb,
                                               float* __restrict__ Anorm,
                                               float* __restrict__ Sabs,
                                               unsigned short* __restrict__ xh,
                                               float* __restrict__ enorm,
                                               float* __restrict__ embT,
                                               unsigned short* __restrict__ ehT) {
    __shared__ float tile[64][68];
    const int b = blockIdx.x;
    const int tid = threadIdx.x;

    if (b < 256) {
        // ---- prepx: Anorm (numpy pairwise), Sabs, xh bf16 ----
        const int gt = b * 256 + tid;
        const int n  = gt >> 1;
        const int h  = gt & 1;
        const float4* __restrict__ xr =
            reinterpret_cast<const float4*>(x + (size_t)n * D) + h * 32;
        unsigned short* __restrict__ xo = xh + (size_t)n * D + h * 128;

        float r[8], sab;
        float4 u = xr[0], v = xr[1];
        {
            short8v p;
            p[0]=(short)bf16rne(u.x); p[1]=(short)bf16rne(u.y);
            p[2]=(short)bf16rne(u.z); p[3]=(short)bf16rne(u.w);
            p[4]=(short)bf16rne(v.x); p[5]=(short)bf16rne(v.y);
            p[6]=(short)bf16rne(v.z); p[7]=(short)bf16rne(v.w);
            *reinterpret_cast<short8v*>(xo) = p;
        }
        r[0]=__fmul_rn(u.x,u.x); r[1]=__fmul_rn(u.y,u.y);
        r[2]=__fmul_rn(u.z,u.z); r[3]=__fmul_rn(u.w,u.w);
        r[4]=__fmul_rn(v.x,v.x); r[5]=__fmul_rn(v.y,v.y);
        r[6]=__fmul_rn(v.z,v.z); r[7]=__fmul_rn(v.w,v.w);
        sab = fabsf(u.x)+fabsf(u.y)+fabsf(u.z)+fabsf(u.w)
            + fabsf(v.x)+fabsf(v.y)+fabsf(v.z)+fabsf(v.w);
        #pragma unroll
        for (int i = 1; i < 16; ++i) {
            u = xr[2*i]; v = xr[2*i+1];
            short8v p;
            p[0]=(short)bf16rne(u.x); p[1]=(short)bf16rne(u.y);
            p[2]=(short)bf16rne(u.z); p[3]=(short)bf16rne(u.w);
            p[4]=(short)bf16rne(v.x); p[5]=(short)bf16rne(v.y);
            p[6]=(short)bf16rne(v.z); p[7]=(short)bf16rne(v.w);
            *reinterpret_cast<short8v*>(xo + i * 8) = p;
            r[0]=__fadd_rn(r[0],__fmul_rn(u.x,u.x));
            r[1]=__fadd_rn(r[1],__fmul_rn(u.y,u.y));
            r[2]=__fadd_rn(r[2],__fmul_rn(u.z,u.z));
            r[3]=__fadd_rn(r[3],__fmul_rn(u.w,u.w));
            r[4]=__fadd_rn(r[4],__fmul_rn(v.x,v.x));
            r[5]=__fadd_rn(r[5],__fmul_rn(v.y,v.y));
            r[6]=__fadd_rn(r[6],__fmul_rn(v.z,v.z));
            r[7]=__fadd_rn(r[7],__fmul_rn(v.w,v.w));
            sab += fabsf(u.x)+fabsf(u.y)+fabsf(u.z)+fabsf(u.w)
                 + fabsf(v.x)+fabsf(v.y)+fabsf(v.z)+fabsf(v.w);
        }
        float ah = __fadd_rn(__fadd_rn(__fadd_rn(r[0],r[1]),__fadd_rn(r[2],r[3])),
                             __fadd_rn(__fadd_rn(r[4],r[5]),__fadd_rn(r[6],r[7])));
        float oh = __shfl_xor(ah, 1);
        float os = __shfl_xor(sab, 1);
        if (h == 0) {
            Anorm[n] = __fadd_rn(ah, oh);   // fl(half0 + half1), numpy order
            Sabs[n]  = sab + os;
        }
    } else if (b < 260) {
        // ---- enorm: numpy axis-0 sequential fp32 sum of squares ----
        // named-scalar 2-bank pipeline (16 coalesced loads in flight)
        int k = (b - 256) * 256 + tid;
        const float* __restrict__ ek = emb + k;
        float c = 0.0f;
        EDECL(ea) EDECL(eb)
        LD8(ea, 0) LD8(eb, 8)
        STEP2E(0)   STEP2E(16)  STEP2E(32)  STEP2E(48)
        STEP2E(64)  STEP2E(80)  STEP2E(96)  STEP2E(112)
        STEP2E(128) STEP2E(144) STEP2E(160) STEP2E(176)
        STEP2E(192) STEP2E(208) STEP2E(224)
        SQ8(ea) SQ8(eb)         // d = 240..255 (no prefetch)
        enorm[k] = c;
    } else {
        // ---- prepe: embT f32 + ehT bf16 (code-major transposes) ----
        const int bb = b - 260;
        const int bk = bb >> 2, bd = bb & 3;
        const int k0 = bk * 64, d0 = bd * 64;
        #pragma unroll
        for (int s = 0; s < 4; ++s) {
            int li = s * 256 + tid;
            int dd = li >> 4, kq = li & 15;
            float4 v = *reinterpret_cast<const float4*>(
                &emb[(size_t)(d0 + dd) * K + k0 + kq * 4]);
            tile[dd][kq*4+0]=v.x; tile[dd][kq*4+1]=v.y;
            tile[dd][kq*4+2]=v.z; tile[dd][kq*4+3]=v.w;
        }
        __syncthreads();
        #pragma unroll
        for (int s = 0; s < 4; ++s) {
            int li = s * 256 + tid;
            int kk = li >> 4, dq = li & 15;
            float4 v;
            v.x = tile[dq*4+0][kk]; v.y = tile[dq*4+1][kk];
            v.z = tile[dq*4+2][kk]; v.w = tile[dq*4+3][kk];
            *reinterpret_cast<float4*>(&embT[(size_t)(k0+kk)*D + d0 + dq*4]) = v;
            us4v hq;
            hq[0]=bf16rne(v.x); hq[1]=bf16rne(v.y);
            hq[2]=bf16rne(v.z); hq[3]=bf16rne(v.w);
            *reinterpret_cast<us4v*>(&ehT[(size_t)(k0+kk)*D + d0 + dq*4]) = hq;
        }
    }
}

// ---- bf16 MFMA screen: 128x128 tile, 4 waves (2x2), 16x16x32 MFMA ----
#define LDSTR 40   // ushorts per LDS row (80B): 16B-aligned, 2-way banks (free)

__global__ __launch_bounds__(256) void vq_screen(const unsigned short* __restrict__ xh,
                                                 const unsigned short* __restrict__ ehT,
                                                 const float* __restrict__ Anorm,
                                                 const float* __restrict__ enorm,
                                                 float* __restrict__ gmin16) {
    __shared__ unsigned short a_lds[128 * LDSTR];
    __shared__ unsigned short b_lds[128 * LDSTR];
    const int tid = threadIdx.x;
    const int l = tid & 63, wid = tid >> 6;
    const int wr = wid >> 1, wc = wid & 1;        // wave tile 64x64
    const int rt = blockIdx.x >> 3, cc = blockIdx.x & 7;
    const int n0 = rt * 128, c0 = cc * 128;
    const int g = l >> 4, cl = l & 15;

    f32x4 acc[4][4];
    #pragma unroll
    for (int mf = 0; mf < 4; ++mf)
        #pragma unroll
        for (int nf = 0; nf < 4; ++nf)
            acc[mf][nf] = (f32x4){0.f, 0.f, 0.f, 0.f};

    const int srow = tid >> 1, sq = (tid & 1) * 2;   // staging: 2x16B per thread
    for (int s = 0; s < 8; ++s) {                    // K = 8 steps of 32
        __syncthreads();
        {
            const short8v* ga = reinterpret_cast<const short8v*>(
                xh + (size_t)(n0 + srow) * D + s * 32 + sq * 8);
            short8v a0 = ga[0], a1 = ga[1];
            *reinterpret_cast<short8v*>(&a_lds[srow * LDSTR + sq * 8])     = a0;
            *reinterpret_cast<short8v*>(&a_lds[srow * LDSTR + sq * 8 + 8]) = a1;
            const short8v* gb = reinterpret_cast<const short8v*>(
                ehT + (size_t)(c0 + srow) * D + s * 32 + sq * 8);
            short8v b0 = gb[0], b1 = gb[1];
            *reinterpret_cast<short8v*>(&b_lds[srow * LDSTR + sq * 8])     = b0;
            *reinterpret_cast<short8v*>(&b_lds[srow * LDSTR + sq * 8 + 8]) = b1;
        }
        __syncthreads();
        short8v af[4], bf[4];
        #pragma unroll
        for (int mf = 0; mf < 4; ++mf)
            af[mf] = *reinterpret_cast<const short8v*>(
                &a_lds[(wr * 64 + mf * 16 + cl) * LDSTR + g * 8]);
        #pragma unroll
        for (int nf = 0; nf < 4; ++nf)
            bf[nf] = *reinterpret_cast<const short8v*>(
                &b_lds[(wc * 64 + nf * 16 + cl) * LDSTR + g * 8]);
        #pragma unroll
        for (int mf = 0; mf < 4; ++mf)
            #pragma unroll
            for (int nf = 0; nf < 4; ++nf)
                acc[mf][nf] = __builtin_amdgcn_mfma_f32_16x16x32_bf16(
                    af[mf], bf[nf], acc[mf][nf], 0, 0, 0);
    }

    // epilogue: screen dist + per-row 16-code group mins
    #pragma unroll
    for (int mf = 0; mf < 4; ++mf) {
        #pragma unroll
        for (int nf = 0; nf < 4; ++nf) {
            f32x4 a = acc[mf][nf];
            const int cg = c0 + wc * 64 + nf * 16 + cl;
            const float C = enorm[cg];
            #pragma unroll
            for (int r = 0; r < 4; ++r) {
                const int ng = n0 + wr * 64 + mf * 16 + g * 4 + r;
                float dist = Anorm[ng] - 2.0f * a[r] + C;
                #pragma unroll
                for (int m = 1; m <= 8; m <<= 1)
                    dist = fminf(dist, __shfl_xor(dist, m));
                if (cl == 0)
                    gmin16[(size_t)ng * 64 + cc * 8 + wc * 4 + nf] = dist;
            }
        }
    }
}

// ---- fused exact rescue + gather/out/loss: one wave per row ----
__global__ __launch_bounds__(256) void vq_rescue_merge(
        const float* __restrict__ x,
        const float* __restrict__ emb,
        const float* __restrict__ embT,
        const float* __restrict__ Anorm,
        const float* __restrict__ Sabs,
        const float* __restrict__ enorm,
        const float* __restrict__ gmin16,
        float* __restrict__ out,
        double* __restrict__ lossacc) {
    __shared__ float xs[4][256];   // one x row per wave, broadcast-read
    const int tid = threadIdx.x, l = tid & 63, w = tid >> 6;
    const int row = blockIdx.x * 4 + w;

    const float4 xv4 = reinterpret_cast<const float4*>(x + (size_t)row * D)[l];
    *reinterpret_cast<float4*>(&xs[w][l * 4]) = xv4;

    float gv = gmin16[(size_t)row * 64 + l];
    float gm = gv;
    #pragma unroll
    for (int m = 1; m < 64; m <<= 1) gm = fminf(gm, __shfl_xor(gm, m));
    // margin identical to the r4 PASSING run (sound: 2*per-code bf16 bound)
    const float margin = fmaf(Sabs[row] * 0.05f, 0.017f, 0.002f);
    unsigned long long mask = __ballot(gv <= gm + margin);

    __syncthreads();   // xs visible

    const float A = Anorm[row];
    const int p   = l >> 4;    // up to 4 groups per pass, one per lane-group
    const int sub = l & 15;
    float bestd = 1e30f; int besti = 0x7fffffff;
    const float4* __restrict__ xs4 = reinterpret_cast<const float4*>(xs[w]);

    while (mask) {
        unsigned long long m = mask;          // p-th set bit (mask wave-uniform)
        if (p > 0) m &= m - 1;
        if (p > 1 && m) m &= m - 1;
        if (p > 2 && m) m &= m - 1;
        const int gp = m ? __builtin_ctzll(m) : __builtin_ctzll(mask); // idle->dup g0
        #pragma unroll
        for (int i = 0; i < 4; ++i) mask &= mask - 1;   // strip <=4 bits (0-safe)

        const int k = gp * 16 + sub;
        const float* __restrict__ ek = emb + k;
        // EXACT reference chain (sequential-d fp32 fmaf) with named-scalar
        // 2-bank ping-pong prefetch: 16 independent loads in flight, zero
        // array traffic. Chain ORDER over d unchanged -> bit-identical dist.
        float c = 0.f;
        EDECL(ea) EDECL(eb)
        LD8(ea, 0) LD8(eb, 8)
        STEP2(0)   STEP2(16)  STEP2(32)  STEP2(48)
        STEP2(64)  STEP2(80)  STEP2(96)  STEP2(112)
        STEP2(128) STEP2(144) STEP2(160) STEP2(176)
        STEP2(192) STEP2(208) STEP2(224)
        FMA8(ea, 240) FMA8(eb, 248)       // d = 240..255 (no prefetch)
        float dist = __fadd_rn(__fsub_rn(A, 2.0f * c), enorm[k]); // fl(fl(A-2B)+C)
        if (dist < bestd || (dist == bestd && k < besti)) { bestd = dist; besti = k; }
    }
    #pragma unroll
    for (int m = 1; m < 64; m <<= 1) {        // lexicographic (dist, idx) min
        float od = __shfl_xor(bestd, m);
        int   oi = __shfl_xor(besti, m);
        if (od < bestd || (od == bestd && oi < besti)) { bestd = od; besti = oi; }
    }
    besti = __shfl(besti, 0);

    // fused merge: gather winning code (code-major, coalesced), write, loss
    const float4 q = reinterpret_cast<const float4*>(embT + (size_t)besti * D)[l];
    reinterpret_cast<float4*>(out + (size_t)row * D)[l] = q;  // exact pass-through
    double lsum = 0.0, dxx;
    dxx = (double)q.x - (double)xv4.x; lsum = fma(dxx, dxx, lsum);
    dxx = (double)q.y - (double)xv4.y; lsum = fma(dxx, dxx, lsum);
    dxx = (double)q.z - (double)xv4.z; lsum = fma(dxx, dxx, lsum);
    dxx = (double)q.w - (double)xv4.w; lsum = fma(dxx, dxx, lsum);
    for (int off = 32; off > 0; off >>= 1) lsum += __shfl_down(lsum, off);
    if (l == 0) atomicAdd(lossacc, lsum);
}

__global__ void vq_loss(const double* __restrict__ lossacc, float* __restrict__ out_loss) {
    if (threadIdx.x == 0 && blockIdx.x == 0) {
        out_loss[0] = (float)(1.25 * (lossacc[0] / (double)((size_t)N_PTS * D)));
    }
}

extern "C" void kernel_launch(void* const* d_in, const int* in_sizes, int n_in,
                              void* d_out, int out_size, void* d_ws, size_t ws_size,
                              hipStream_t stream) {
    const float* x   = (const float*)d_in[0];
    const float* emb = (const float*)d_in[1];
    float* out = (float*)d_out;
    char* ws = (char*)d_ws;

    float*  enorm   = (float*)(ws);
    double* lossacc = (double*)(ws + 8192);
    float*  Anorm   = (float*)(ws + 16384);
    float*  Sabs    = (float*)(ws + 147456);
    unsigned short* ehT = (unsigned short*)(ws + 409600);
    float*  embT    = (float*)(ws + 933888);
    float*  gmin16  = (float*)(ws + 1982464);           // 8 MB, ends ~10.4 MB
    unsigned short* xh = (unsigned short*)out;          // d_out scratch

    hipMemsetAsync(lossacc, 0, sizeof(double), stream);
    vq_prep<<<256 + 4 + 64, 256, 0, stream>>>(x, emb, Anorm, Sabs, xh,
                                              enorm, embT, ehT);
    vq_screen<<<(N_PTS / 128) * (K / 128), 256, 0, stream>>>(xh, ehT, Anorm, enorm, gmin16);
    vq_rescue_merge<<<N_PTS / 4, 256, 0, stream>>>(x, emb, embT, Anorm, Sabs,
                                                   enorm, gmin16, out, lossacc);
    vq_loss<<<1, 64, 0, stream>>>(lossacc, out + (size_t)N_PTS * D);
}